// Round 15
// baseline (336.572 us; speedup 1.0000x reference)
//
#include <hip/hip_runtime.h>
#include <hip/hip_fp16.h>

#define N_USERS 40000
#define N_ITEMS 20000
#define N_TOTAL (N_USERS + N_ITEMS)
#define D 64
#define G_BKT ((N_ITEMS + 63) >> 6)   // 313 buckets of 64 items
#define PAD 16                         // one counter per 64B line

union H8 { uint4 u; __half h[8]; };

// native vector types for nontemporal builtins (HIP_vector_type not accepted)
typedef unsigned int u32x4 __attribute__((ext_vector_type(4)));
typedef float f32x4 __attribute__((ext_vector_type(4)));
typedef int i32x2 __attribute__((ext_vector_type(2)));

#define NTL(x) __builtin_nontemporal_load(&(x))

__device__ __forceinline__ void nt_store_u4(uint4 v, void* p) {
    u32x4 t = { v.x, v.y, v.z, v.w };
    __builtin_nontemporal_store(t, (u32x4*)p);
}
__device__ __forceinline__ void nt_store_f4(float4 v, void* p) {
    f32x4 t = { v.x, v.y, v.z, v.w };
    __builtin_nontemporal_store(t, (f32x4*)p);
}
__device__ __forceinline__ int2 nt_load_i2(const void* p) {
    i32x2 t = __builtin_nontemporal_load((const i32x2*)p);
    return make_int2(t.x, t.y);
}

// XCD-partitioned row mapping for full-graph kernels (2000 blocks x 256 thr):
// blockIdx%8 in 0..4 -> user rows (those XCDs gather only the 2.56MB item half);
// blockIdx%8 in 5..7 -> item rows (gather the 5.12MB user half).
// 1250 user blocks (5x250), 625 item blocks (209,209,207). Returns -1 if idle.
__device__ __forceinline__ int map_row(int bid, int wib, int g) {
    int x = bid & 7, s = bid >> 3;
    if (x < 5) {
        int ub = x * 250 + s;
        if (ub >= 1250) return -1;
        return ub * 32 + wib * 8 + g;
    } else {
        int si = x - 5;
        int cnt = (si == 2) ? 207 : 209;
        if (s >= cnt) return -1;
        return N_USERS + (si * 209 + s) * 32 + wib * 8 + g;
    }
}
#define GRID_FULL 2000

// ---------------- fused setup: tohalf(ul) + tohalf(il) + rowptr_u + zero(bcnt) ----------------
#define ZA (N_ITEMS * D / 8)                 // 160000
#define ZB (N_USERS * D / 8)                 // 320000
#define ZC (N_USERS + 1)                     // 40001
#define ZD ((G_BKT + 1) * PAD)               // 5024
#define ZTOT (ZA + ZB + ZC + ZD)

__global__ void setup_kernel(const float* __restrict__ ul, const float* __restrict__ il,
                             const int* __restrict__ u_idx,
                             __half* __restrict__ ulH, __half* __restrict__ ilH,
                             int* __restrict__ pu, int* __restrict__ bcnt, int nnz) {
    int t = blockIdx.x * blockDim.x + threadIdx.x;
    if (t < ZA) {
        const float4* s = (const float4*)(ul + (size_t)t * 8);
        float4 a = s[0], b = s[1];
        H8 o;
        o.h[0] = __float2half(a.x); o.h[1] = __float2half(a.y);
        o.h[2] = __float2half(a.z); o.h[3] = __float2half(a.w);
        o.h[4] = __float2half(b.x); o.h[5] = __float2half(b.y);
        o.h[6] = __float2half(b.z); o.h[7] = __float2half(b.w);
        ((uint4*)ulH)[t] = o.u;
    } else if (t < ZA + ZB) {
        int q = t - ZA;
        const float4* s = (const float4*)(il + (size_t)q * 8);
        float4 a = s[0], b = s[1];
        H8 o;
        o.h[0] = __float2half(a.x); o.h[1] = __float2half(a.y);
        o.h[2] = __float2half(a.z); o.h[3] = __float2half(a.w);
        o.h[4] = __float2half(b.x); o.h[5] = __float2half(b.y);
        o.h[6] = __float2half(b.z); o.h[7] = __float2half(b.w);
        ((uint4*)ilH)[q] = o.u;
    } else if (t < ZA + ZB + ZC) {
        int u = t - (ZA + ZB);
        int lo = 0, hi = nnz;
        while (lo < hi) { int mid = (lo + hi) >> 1; if (u_idx[mid] < u) lo = mid + 1; else hi = mid; }
        pu[u] = lo;
    } else if (t < ZTOT) {
        bcnt[t - (ZA + ZB + ZC)] = 0;
    }
}

// ---------------- CSR transpose (2-phase bucketed) ----------------

__global__ void bcount_kernel(const int* __restrict__ i_idx, int* __restrict__ bcnt, int nnz) {
    __shared__ int lc[G_BKT];
    for (int t = threadIdx.x; t < G_BKT; t += blockDim.x) lc[t] = 0;
    __syncthreads();
    int stride = gridDim.x * blockDim.x;
    for (int e = blockIdx.x * blockDim.x + threadIdx.x; e < nnz; e += stride)
        atomicAdd(&lc[__builtin_nontemporal_load(i_idx + e) >> 6], 1);
    __syncthreads();
    for (int t = threadIdx.x; t < G_BKT; t += blockDim.x)
        if (lc[t]) atomicAdd(bcnt + t * PAD, lc[t]);
}

__global__ void bscan_kernel(const int* __restrict__ bcnt, int* __restrict__ bbase,
                             int* __restrict__ bcur, int* __restrict__ pi, int nnz) {
    if (threadIdx.x == 0 && blockIdx.x == 0) {
        int run = 0;
        for (int g = 0; g < G_BKT; ++g) {
            bbase[g * PAD] = run;
            bcur[g * PAD] = run;
            run += bcnt[g * PAD];
        }
        bbase[G_BKT * PAD] = run;   // == nnz
        pi[N_ITEMS] = run;
    }
}

__global__ void p1_kernel(const int* __restrict__ i_idx, const int* __restrict__ u_idx,
                          int* __restrict__ bcur, int2* __restrict__ tmp, int nnz) {
    const int E = 8;
    __shared__ int lc[G_BKT];
    __shared__ int gb[G_BKT];
    for (int t = threadIdx.x; t < G_BKT; t += blockDim.x) lc[t] = 0;
    __syncthreads();
    int base_e = blockIdx.x * blockDim.x * E;
    int myb[E], myr[E]; int2 myv[E];
    #pragma unroll
    for (int j = 0; j < E; ++j) {
        int e = base_e + j * blockDim.x + threadIdx.x;  // coalesced
        myb[j] = -1;
        if (e < nnz) {
            int i = __builtin_nontemporal_load(i_idx + e);
            int u = __builtin_nontemporal_load(u_idx + e);
            int b = i >> 6;
            myb[j] = b;
            myr[j] = atomicAdd(&lc[b], 1);
            myv[j] = make_int2(e, (i << 16) | u);
        }
    }
    __syncthreads();
    for (int t = threadIdx.x; t < G_BKT; t += blockDim.x)
        gb[t] = lc[t] ? atomicAdd(bcur + t * PAD, lc[t]) : 0;
    __syncthreads();
    #pragma unroll
    for (int j = 0; j < E; ++j)
        if (myb[j] >= 0) tmp[gb[myb[j]] + myr[j]] = myv[j];
}

// phase 2: one block per bucket; writes eids + col2 (separate contiguous arrays)
__global__ void p2_kernel(const int2* __restrict__ tmp, const int* __restrict__ bbase,
                          int* __restrict__ pi, int* __restrict__ eids, int* __restrict__ col2) {
    __shared__ int hist[64];
    __shared__ int cur[64];
    int g = blockIdx.x;
    int t = threadIdx.x;
    if (t < 64) { hist[t] = 0; cur[t] = 0; }
    __syncthreads();
    int base = bbase[g * PAD], end = bbase[(g + 1) * PAD];
    int lo_item = g << 6;
    for (int k = base + t; k < end; k += blockDim.x)
        atomicAdd(&hist[(nt_load_i2(&tmp[k]).y >> 16) & 63], 1);
    __syncthreads();
    if (t == 0) {
        int run = base;
        for (int x = 0; x < 64; ++x) {
            int c = hist[x];
            hist[x] = run;
            if (lo_item + x < N_ITEMS) pi[lo_item + x] = run;
            run += c;
        }
    }
    __syncthreads();
    for (int k = base + t; k < end; k += blockDim.x) {
        int2 v = nt_load_i2(&tmp[k]);
        int li = (v.y >> 16) & 63;
        int pos = atomicAdd(&cur[li], 1);
        int dst = hist[li] + pos;
        eids[dst] = v.x;
        col2[dst] = v.y & 0xFFFF;
    }
}

// ---------------- embeddings (emb + invnorm; XCD-partitioned; nt streams) ----------------
__global__ void emb_kernel(const __half* __restrict__ ulH, const __half* __restrict__ ilH,
                           const int* __restrict__ i_idx, const int* __restrict__ col2,
                           const int* __restrict__ pu, const int* __restrict__ pi,
                           __half* __restrict__ embH, float* __restrict__ invn) {
    int wib = threadIdx.x >> 6, lane = threadIdx.x & 63;
    int g = lane >> 3, c = lane & 7;
    int row = map_row(blockIdx.x, wib, g);
    if (row < 0) return;
    float s[8];
    #pragma unroll
    for (int j = 0; j < 8; ++j) s[j] = 0.f;
    const __half* tbl; const int* cols; int b, e;
    if (row < N_USERS) { tbl = ulH; cols = i_idx; b = pu[row]; e = pu[row + 1]; }
    else { int i = row - N_USERS; tbl = ilH; cols = col2; b = pi[i]; e = pi[i + 1]; }
    int k = b;
    for (; k + 3 < e; k += 4) {
        int i0 = NTL(cols[k]), i1 = NTL(cols[k + 1]), i2 = NTL(cols[k + 2]), i3 = NTL(cols[k + 3]);
        H8 r0, r1, r2, r3;
        r0.u = ((const uint4*)(tbl + (size_t)i0 * D))[c];
        r1.u = ((const uint4*)(tbl + (size_t)i1 * D))[c];
        r2.u = ((const uint4*)(tbl + (size_t)i2 * D))[c];
        r3.u = ((const uint4*)(tbl + (size_t)i3 * D))[c];
        #pragma unroll
        for (int q = 0; q < 8; ++q)
            s[q] += (__half2float(r0.h[q]) + __half2float(r1.h[q]))
                  + (__half2float(r2.h[q]) + __half2float(r3.h[q]));
    }
    for (; k < e; ++k) {
        H8 r0;
        r0.u = ((const uint4*)(tbl + (size_t)NTL(cols[k]) * D))[c];
        #pragma unroll
        for (int q = 0; q < 8; ++q) s[q] += __half2float(r0.h[q]);
    }
    float nsq = 0.f;
    #pragma unroll
    for (int q = 0; q < 8; ++q) nsq += s[q] * s[q];
    #pragma unroll
    for (int m = 1; m < 8; m <<= 1) nsq += __shfl_xor(nsq, m, 64);   // intra-group
    H8 o;
    #pragma unroll
    for (int q = 0; q < 8; ++q) o.h[q] = __float2half(s[q]);
    nt_store_u4(o.u, (uint4*)(embH + (size_t)row * D) + c);
    if (c == 0) invn[row] = 1.f / fmaxf(sqrtf(nsq), 1e-8f);
}

// ---------------- fused sims + prop-layer-1 USER side ----------------
__global__ void fsp1u_kernel(const __half* __restrict__ embA, const float* __restrict__ invn,
                             const int* __restrict__ i_idx, const int* __restrict__ pu,
                             float* __restrict__ sims, float* __restrict__ diag,
                             __half* __restrict__ embB) {
    int tid = blockIdx.x * blockDim.x + threadIdx.x;
    int wave = tid >> 6, lane = threadIdx.x & 63;
    int g = lane >> 3, c = lane & 7;
    int u = wave * 8 + g;
    if (u >= N_USERS) return;
    float invu = invn[u];
    H8 ur; ur.u = ((const uint4*)(embA + (size_t)u * D))[c];
    float un[8];
    #pragma unroll
    for (int q = 0; q < 8; ++q) un[q] = __half2float(ur.h[q]) * invu;
    float s[8];
    #pragma unroll
    for (int q = 0; q < 8; ++q) s[q] = 0.f;
    float dsum = 0.f;
    int b = pu[u], e = pu[u + 1];
    int k = b;
    for (; k + 3 < e; k += 4) {
        int i0 = NTL(i_idx[k]), i1 = NTL(i_idx[k + 1]), i2 = NTL(i_idx[k + 2]), i3 = NTL(i_idx[k + 3]);
        H8 r0, r1, r2, r3;
        r0.u = ((const uint4*)(embA + (size_t)(N_USERS + i0) * D))[c];
        r1.u = ((const uint4*)(embA + (size_t)(N_USERS + i1) * D))[c];
        r2.u = ((const uint4*)(embA + (size_t)(N_USERS + i2) * D))[c];
        r3.u = ((const uint4*)(embA + (size_t)(N_USERS + i3) * D))[c];
        float iv0 = invn[N_USERS + i0], iv1 = invn[N_USERS + i1];
        float iv2 = invn[N_USERS + i2], iv3 = invn[N_USERS + i3];
        float d0 = 0.f, d1 = 0.f, d2 = 0.f, d3 = 0.f;
        #pragma unroll
        for (int q = 0; q < 8; ++q) {
            d0 += un[q] * __half2float(r0.h[q]);
            d1 += un[q] * __half2float(r1.h[q]);
            d2 += un[q] * __half2float(r2.h[q]);
            d3 += un[q] * __half2float(r3.h[q]);
        }
        #pragma unroll
        for (int m = 1; m < 8; m <<= 1) {
            d0 += __shfl_xor(d0, m, 64); d1 += __shfl_xor(d1, m, 64);
            d2 += __shfl_xor(d2, m, 64); d3 += __shfl_xor(d3, m, 64);
        }
        float sv0 = (d0 * iv0 + 1.f) * 0.5f;
        float sv1 = (d1 * iv1 + 1.f) * 0.5f;
        float sv2 = (d2 * iv2 + 1.f) * 0.5f;
        float sv3 = (d3 * iv3 + 1.f) * 0.5f;
        if (c == 0) {
            __builtin_nontemporal_store(sv0, sims + k);
            __builtin_nontemporal_store(sv1, sims + k + 1);
            __builtin_nontemporal_store(sv2, sims + k + 2);
            __builtin_nontemporal_store(sv3, sims + k + 3);
        }
        dsum += (sv0 + sv1) + (sv2 + sv3);
        #pragma unroll
        for (int q = 0; q < 8; ++q)
            s[q] += (sv0 * __half2float(r0.h[q]) + sv1 * __half2float(r1.h[q]))
                  + (sv2 * __half2float(r2.h[q]) + sv3 * __half2float(r3.h[q]));
    }
    for (; k < e; ++k) {
        int i0 = NTL(i_idx[k]);
        H8 r0;
        r0.u = ((const uint4*)(embA + (size_t)(N_USERS + i0) * D))[c];
        float iv0 = invn[N_USERS + i0];
        float d0 = 0.f;
        #pragma unroll
        for (int q = 0; q < 8; ++q) d0 += un[q] * __half2float(r0.h[q]);
        #pragma unroll
        for (int m = 1; m < 8; m <<= 1) d0 += __shfl_xor(d0, m, 64);
        float sv0 = (d0 * iv0 + 1.f) * 0.5f;
        if (c == 0) __builtin_nontemporal_store(sv0, sims + k);
        dsum += sv0;
        #pragma unroll
        for (int q = 0; q < 8; ++q) s[q] += sv0 * __half2float(r0.h[q]);
    }
    if (c == 0) diag[u] = dsum;
    float invd = 1.f / (dsum + 1e-7f);
    H8 o;
    #pragma unroll
    for (int q = 0; q < 8; ++q) o.h[q] = __float2half(s[q] * invd);
    nt_store_u4(o.u, (uint4*)(embB + (size_t)u * D) + c);
}

// ---------------- fused w2/diag + prop-layer-1 ITEM side ----------------
__global__ void p1i_kernel(const __half* __restrict__ embA, const float* __restrict__ sims,
                           const int* __restrict__ eids, const int* __restrict__ col2,
                           const int* __restrict__ pi, float* __restrict__ w2,
                           float* __restrict__ diag, __half* __restrict__ embB) {
    int tid = blockIdx.x * blockDim.x + threadIdx.x;
    int wave = tid >> 6, lane = threadIdx.x & 63;
    int g = lane >> 3, c = lane & 7;
    int i = wave * 8 + g;
    if (i >= N_ITEMS) return;
    float s[8];
    #pragma unroll
    for (int q = 0; q < 8; ++q) s[q] = 0.f;
    float dsum = 0.f;
    int b = pi[i], e = pi[i + 1];
    int k = b;
    for (; k + 3 < e; k += 4) {
        int e0 = NTL(eids[k]), e1 = NTL(eids[k + 1]), e2 = NTL(eids[k + 2]), e3 = NTL(eids[k + 3]);
        int u0 = NTL(col2[k]), u1 = NTL(col2[k + 1]), u2 = NTL(col2[k + 2]), u3 = NTL(col2[k + 3]);
        float w0 = sims[e0], w1 = sims[e1], w2v = sims[e2], w3v = sims[e3];
        H8 r0, r1, r2, r3;
        r0.u = ((const uint4*)(embA + (size_t)u0 * D))[c];
        r1.u = ((const uint4*)(embA + (size_t)u1 * D))[c];
        r2.u = ((const uint4*)(embA + (size_t)u2 * D))[c];
        r3.u = ((const uint4*)(embA + (size_t)u3 * D))[c];
        if (c == 0) {
            __builtin_nontemporal_store(w0, w2 + k);
            __builtin_nontemporal_store(w1, w2 + k + 1);
            __builtin_nontemporal_store(w2v, w2 + k + 2);
            __builtin_nontemporal_store(w3v, w2 + k + 3);
        }
        dsum += (w0 + w1) + (w2v + w3v);
        #pragma unroll
        for (int q = 0; q < 8; ++q)
            s[q] += (w0 * __half2float(r0.h[q]) + w1 * __half2float(r1.h[q]))
                  + (w2v * __half2float(r2.h[q]) + w3v * __half2float(r3.h[q]));
    }
    for (; k < e; ++k) {
        float w0 = sims[NTL(eids[k])];
        H8 r0;
        r0.u = ((const uint4*)(embA + (size_t)NTL(col2[k]) * D))[c];
        if (c == 0) __builtin_nontemporal_store(w0, w2 + k);
        dsum += w0;
        #pragma unroll
        for (int q = 0; q < 8; ++q) s[q] += w0 * __half2float(r0.h[q]);
    }
    if (c == 0) diag[N_USERS + i] = dsum;
    float invd = 1.f / (dsum + 1e-7f);
    H8 o;
    #pragma unroll
    for (int q = 0; q < 8; ++q) o.h[q] = __float2half(s[q] * invd);
    nt_store_u4(o.u, (uint4*)(embB + (size_t)(N_USERS + i) * D) + c);
}

// ---------------- propagation layers 2/3 (XCD-partitioned; nt streams) ----------------
template <bool FINAL>
__global__ void prop_kernel(const __half* __restrict__ curH, __half* __restrict__ nextH,
                            const float* __restrict__ sims, const float* __restrict__ w2,
                            const float* __restrict__ diag,
                            const int* __restrict__ i_idx, const int* __restrict__ col2,
                            const int* __restrict__ pu, const int* __restrict__ pi,
                            const __half* __restrict__ e0, const __half* __restrict__ e1,
                            const __half* __restrict__ e2, float* __restrict__ out) {
    int wib = threadIdx.x >> 6, lane = threadIdx.x & 63;
    int g = lane >> 3, c = lane & 7;
    int row = map_row(blockIdx.x, wib, g);
    if (row < 0) return;
    float s[8];
    #pragma unroll
    for (int j = 0; j < 8; ++j) s[j] = 0.f;
    const int* cols; const float* ws; int b, e, colOff;
    if (row < N_USERS) { b = pu[row]; e = pu[row + 1]; cols = i_idx; ws = sims; colOff = N_USERS; }
    else { int i = row - N_USERS; b = pi[i]; e = pi[i + 1]; cols = col2; ws = w2; colOff = 0; }
    int k = b;
    for (; k + 3 < e; k += 4) {
        int i0 = NTL(cols[k]) + colOff, i1 = NTL(cols[k + 1]) + colOff,
            i2 = NTL(cols[k + 2]) + colOff, i3 = NTL(cols[k + 3]) + colOff;
        float w0 = NTL(ws[k]), w1 = NTL(ws[k + 1]), w2v = NTL(ws[k + 2]), w3v = NTL(ws[k + 3]);
        H8 r0, r1, r2, r3;
        r0.u = ((const uint4*)(curH + (size_t)i0 * D))[c];
        r1.u = ((const uint4*)(curH + (size_t)i1 * D))[c];
        r2.u = ((const uint4*)(curH + (size_t)i2 * D))[c];
        r3.u = ((const uint4*)(curH + (size_t)i3 * D))[c];
        #pragma unroll
        for (int q = 0; q < 8; ++q)
            s[q] += (w0 * __half2float(r0.h[q]) + w1 * __half2float(r1.h[q]))
                  + (w2v * __half2float(r2.h[q]) + w3v * __half2float(r3.h[q]));
    }
    for (; k < e; ++k) {
        float w0 = NTL(ws[k]);
        H8 r0;
        r0.u = ((const uint4*)(curH + (size_t)(NTL(cols[k]) + colOff) * D))[c];
        #pragma unroll
        for (int q = 0; q < 8; ++q) s[q] += w0 * __half2float(r0.h[q]);
    }
    float invd = 1.f / (diag[row] + 1e-7f);
    float v[8];
    #pragma unroll
    for (int q = 0; q < 8; ++q) v[q] = s[q] * invd;
    if (FINAL) {
        H8 r0, r1, r2;
        u32x4 t0 = __builtin_nontemporal_load((const u32x4*)(e0 + (size_t)row * D) + c);
        u32x4 t1 = __builtin_nontemporal_load((const u32x4*)(e1 + (size_t)row * D) + c);
        u32x4 t2 = __builtin_nontemporal_load((const u32x4*)(e2 + (size_t)row * D) + c);
        r0.u = make_uint4(t0.x, t0.y, t0.z, t0.w);
        r1.u = make_uint4(t1.x, t1.y, t1.z, t1.w);
        r2.u = make_uint4(t2.x, t2.y, t2.z, t2.w);
        float o[8];
        #pragma unroll
        for (int q = 0; q < 8; ++q)
            o[q] = (v[q] + __half2float(r0.h[q]) + __half2float(r1.h[q]) + __half2float(r2.h[q])) * 0.25f;
        float4* op = (float4*)(out + (size_t)row * D);
        nt_store_f4(make_float4(o[0], o[1], o[2], o[3]), op + c * 2);
        nt_store_f4(make_float4(o[4], o[5], o[6], o[7]), op + c * 2 + 1);
    } else {
        H8 o;
        #pragma unroll
        for (int q = 0; q < 8; ++q) o.h[q] = __float2half(v[q]);
        nt_store_u4(o.u, (uint4*)(nextH + (size_t)row * D) + c);
    }
}

// ---------------- launch ----------------

extern "C" void kernel_launch(void* const* d_in, const int* in_sizes, int n_in,
                              void* d_out, int out_size, void* d_ws, size_t ws_size,
                              hipStream_t stream) {
    const float* user_linear = (const float*)d_in[0];
    const float* item_linear = (const float*)d_in[1];
    const int* u_idx = (const int*)d_in[2];
    const int* i_idx = (const int*)d_in[3];
    const int nnz = in_sizes[2];

    // carve workspace (256B aligned)
    char* p = (char*)d_ws;
    auto carve = [&](size_t bytes) { void* r = (void*)p; p += (bytes + 255) & ~(size_t)255; return r; };
    __half* embA = (__half*)carve((size_t)N_TOTAL * D * 2);
    __half* embB = (__half*)carve((size_t)N_TOTAL * D * 2);
    __half* embC = (__half*)carve((size_t)N_TOTAL * D * 2);
    __half* ulH  = (__half*)carve((size_t)N_ITEMS * D * 2);
    __half* ilH  = (__half*)carve((size_t)N_USERS * D * 2);
    float* sims = (float*)carve((size_t)nnz * 4);
    float* w2   = (float*)carve((size_t)nnz * 4);
    float* diag = (float*)carve((size_t)N_TOTAL * 4);
    float* invn = (float*)carve((size_t)N_TOTAL * 4);
    int* pu   = (int*)carve((size_t)(N_USERS + 1) * 4);
    int* pi   = (int*)carve((size_t)(N_ITEMS + 1) * 4);
    int* eids = (int*)carve((size_t)nnz * 4);
    int* col2 = (int*)carve((size_t)nnz * 4);
    int* bcnt  = (int*)carve((size_t)(G_BKT + 1) * PAD * 4);
    int* bbase = (int*)carve((size_t)(G_BKT + 1) * PAD * 4);
    int* bcur  = (int*)carve((size_t)(G_BKT + 1) * PAD * 4);

    // staging aliases embA+embB (15.36MB >= 8MB); both dead until emb_kernel
    int2* tmp = (int2*)embA;

    float* out = (float*)d_out;  // [N_TOTAL, D]

    const int B = 256;

    // fused setup (tohalf x2, rowptr_u, bcnt zero) + CSR transpose
    setup_kernel<<<(ZTOT + B - 1) / B, B, 0, stream>>>(user_linear, item_linear, u_idx,
                                                       ulH, ilH, pu, bcnt, nnz);
    bcount_kernel<<<256, B, 0, stream>>>(i_idx, bcnt, nnz);
    bscan_kernel<<<1, 64, 0, stream>>>(bcnt, bbase, bcur, pi, nnz);
    p1_kernel<<<(nnz + B * 8 - 1) / (B * 8), B, 0, stream>>>(i_idx, u_idx, bcur, tmp, nnz);
    p2_kernel<<<G_BKT, B, 0, stream>>>(tmp, bbase, pi, eids, col2);

    // embeddings (+invnorm)  [overwrites tmp region — tmp dead now]
    emb_kernel<<<GRID_FULL, B, 0, stream>>>(ulH, ilH, i_idx, col2, pu, pi, embA, invn);

    // layer 1 fused: user side (sims+diag_u+prop) then item side (w2+diag_i+prop)
    int uThreads = ((N_USERS + 7) / 8) * 64;
    fsp1u_kernel<<<(uThreads + B - 1) / B, B, 0, stream>>>(embA, invn, i_idx, pu,
                                                           sims, diag, embB);
    int iThreads = ((N_ITEMS + 7) / 8) * 64;
    p1i_kernel<<<(iThreads + B - 1) / B, B, 0, stream>>>(embA, sims, eids, col2, pi,
                                                         w2, diag, embB);

    // layers 2 and 3; final fuses the 4-embedding mean into d_out
    prop_kernel<false><<<GRID_FULL, B, 0, stream>>>(embB, embC, sims, w2, diag,
                                                    i_idx, col2, pu, pi,
                                                    nullptr, nullptr, nullptr, nullptr);
    prop_kernel<true><<<GRID_FULL, B, 0, stream>>>(embC, nullptr, sims, w2, diag,
                                                   i_idx, col2, pu, pi,
                                                   embA, embB, embC, out);
}

// Round 16
// 232.692 us; speedup vs baseline: 1.4464x; 1.4464x over previous
//
#include <hip/hip_runtime.h>
#include <hip/hip_fp16.h>

#define N_USERS 40000
#define N_ITEMS 20000
#define N_TOTAL (N_USERS + N_ITEMS)
#define D 64
#define G_BKT ((N_ITEMS + 63) >> 6)   // 313 buckets of 64 items
#define PAD 16                         // one counter per 64B line

union H8 { uint4 u; __half h[8]; };

// ---------------- fused setup: tohalf(ul) + tohalf(il) + rowptr_u + zero(bcnt) ----------------
#define ZA (N_ITEMS * D / 8)                 // 160000
#define ZB (N_USERS * D / 8)                 // 320000
#define ZC (N_USERS + 1)                     // 40001
#define ZD ((G_BKT + 1) * PAD)               // 5024
#define ZTOT (ZA + ZB + ZC + ZD)

__global__ void setup_kernel(const float* __restrict__ ul, const float* __restrict__ il,
                             const int* __restrict__ u_idx,
                             __half* __restrict__ ulH, __half* __restrict__ ilH,
                             int* __restrict__ pu, int* __restrict__ bcnt, int nnz) {
    int t = blockIdx.x * blockDim.x + threadIdx.x;
    if (t < ZA) {
        const float4* s = (const float4*)(ul + (size_t)t * 8);
        float4 a = s[0], b = s[1];
        H8 o;
        o.h[0] = __float2half(a.x); o.h[1] = __float2half(a.y);
        o.h[2] = __float2half(a.z); o.h[3] = __float2half(a.w);
        o.h[4] = __float2half(b.x); o.h[5] = __float2half(b.y);
        o.h[6] = __float2half(b.z); o.h[7] = __float2half(b.w);
        ((uint4*)ulH)[t] = o.u;
    } else if (t < ZA + ZB) {
        int q = t - ZA;
        const float4* s = (const float4*)(il + (size_t)q * 8);
        float4 a = s[0], b = s[1];
        H8 o;
        o.h[0] = __float2half(a.x); o.h[1] = __float2half(a.y);
        o.h[2] = __float2half(a.z); o.h[3] = __float2half(a.w);
        o.h[4] = __float2half(b.x); o.h[5] = __float2half(b.y);
        o.h[6] = __float2half(b.z); o.h[7] = __float2half(b.w);
        ((uint4*)ilH)[q] = o.u;
    } else if (t < ZA + ZB + ZC) {
        int u = t - (ZA + ZB);
        int lo = 0, hi = nnz;
        while (lo < hi) { int mid = (lo + hi) >> 1; if (u_idx[mid] < u) lo = mid + 1; else hi = mid; }
        pu[u] = lo;
    } else if (t < ZTOT) {
        bcnt[t - (ZA + ZB + ZC)] = 0;
    }
}

// ---------------- CSR transpose (2-phase bucketed) ----------------

__global__ void bcount_kernel(const int* __restrict__ i_idx, int* __restrict__ bcnt, int nnz) {
    __shared__ int lc[G_BKT];
    for (int t = threadIdx.x; t < G_BKT; t += blockDim.x) lc[t] = 0;
    __syncthreads();
    int stride = gridDim.x * blockDim.x;
    for (int e = blockIdx.x * blockDim.x + threadIdx.x; e < nnz; e += stride)
        atomicAdd(&lc[__builtin_nontemporal_load(i_idx + e) >> 6], 1);
    __syncthreads();
    for (int t = threadIdx.x; t < G_BKT; t += blockDim.x)
        if (lc[t]) atomicAdd(bcnt + t * PAD, lc[t]);
}

__global__ void bscan_kernel(const int* __restrict__ bcnt, int* __restrict__ bbase,
                             int* __restrict__ bcur, int* __restrict__ pi, int nnz) {
    if (threadIdx.x == 0 && blockIdx.x == 0) {
        int run = 0;
        for (int g = 0; g < G_BKT; ++g) {
            bbase[g * PAD] = run;
            bcur[g * PAD] = run;
            run += bcnt[g * PAD];
        }
        bbase[G_BKT * PAD] = run;   // == nnz
        pi[N_ITEMS] = run;
    }
}

__global__ void p1_kernel(const int* __restrict__ i_idx, const int* __restrict__ u_idx,
                          int* __restrict__ bcur, int2* __restrict__ tmp, int nnz) {
    const int E = 8;
    __shared__ int lc[G_BKT];
    __shared__ int gb[G_BKT];
    for (int t = threadIdx.x; t < G_BKT; t += blockDim.x) lc[t] = 0;
    __syncthreads();
    int base_e = blockIdx.x * blockDim.x * E;
    int myb[E], myr[E]; int2 myv[E];
    #pragma unroll
    for (int j = 0; j < E; ++j) {
        int e = base_e + j * blockDim.x + threadIdx.x;  // coalesced
        myb[j] = -1;
        if (e < nnz) {
            int i = __builtin_nontemporal_load(i_idx + e);
            int u = __builtin_nontemporal_load(u_idx + e);
            int b = i >> 6;
            myb[j] = b;
            myr[j] = atomicAdd(&lc[b], 1);
            myv[j] = make_int2(e, (i << 16) | u);
        }
    }
    __syncthreads();
    for (int t = threadIdx.x; t < G_BKT; t += blockDim.x)
        gb[t] = lc[t] ? atomicAdd(bcur + t * PAD, lc[t]) : 0;
    __syncthreads();
    #pragma unroll
    for (int j = 0; j < E; ++j)
        if (myb[j] >= 0) tmp[gb[myb[j]] + myr[j]] = myv[j];
}

// phase 2: one block per bucket; writes eids + col2 (separate contiguous arrays)
__global__ void p2_kernel(const int2* __restrict__ tmp, const int* __restrict__ bbase,
                          int* __restrict__ pi, int* __restrict__ eids, int* __restrict__ col2) {
    __shared__ int hist[64];
    __shared__ int cur[64];
    int g = blockIdx.x;
    int t = threadIdx.x;
    if (t < 64) { hist[t] = 0; cur[t] = 0; }
    __syncthreads();
    int base = bbase[g * PAD], end = bbase[(g + 1) * PAD];
    int lo_item = g << 6;
    for (int k = base + t; k < end; k += blockDim.x)
        atomicAdd(&hist[(tmp[k].y >> 16) & 63], 1);
    __syncthreads();
    if (t == 0) {
        int run = base;
        for (int x = 0; x < 64; ++x) {
            int c = hist[x];
            hist[x] = run;
            if (lo_item + x < N_ITEMS) pi[lo_item + x] = run;
            run += c;
        }
    }
    __syncthreads();
    for (int k = base + t; k < end; k += blockDim.x) {
        int2 v = tmp[k];
        int li = (v.y >> 16) & 63;
        int pos = atomicAdd(&cur[li], 1);
        int dst = hist[li] + pos;
        eids[dst] = v.x;
        col2[dst] = v.y & 0xFFFF;
    }
}

// ---------------- embeddings (emb + invnorm; group-per-row, 4-way unrolled) ----------------
__global__ void emb_kernel(const __half* __restrict__ ulH, const __half* __restrict__ ilH,
                           const int* __restrict__ i_idx, const int* __restrict__ col2,
                           const int* __restrict__ pu, const int* __restrict__ pi,
                           __half* __restrict__ embH, float* __restrict__ invn) {
    int tid = blockIdx.x * blockDim.x + threadIdx.x;
    int wave = tid >> 6, lane = threadIdx.x & 63;
    int g = lane >> 3, c = lane & 7;
    int row = wave * 8 + g;
    if (row >= N_TOTAL) return;
    float s[8];
    #pragma unroll
    for (int j = 0; j < 8; ++j) s[j] = 0.f;
    const __half* tbl; const int* cols; int b, e;
    if (row < N_USERS) { tbl = ulH; cols = i_idx; b = pu[row]; e = pu[row + 1]; }
    else { int i = row - N_USERS; tbl = ilH; cols = col2; b = pi[i]; e = pi[i + 1]; }
    int k = b;
    for (; k + 3 < e; k += 4) {
        int i0 = cols[k], i1 = cols[k + 1], i2 = cols[k + 2], i3 = cols[k + 3];
        H8 r0, r1, r2, r3;
        r0.u = ((const uint4*)(tbl + (size_t)i0 * D))[c];
        r1.u = ((const uint4*)(tbl + (size_t)i1 * D))[c];
        r2.u = ((const uint4*)(tbl + (size_t)i2 * D))[c];
        r3.u = ((const uint4*)(tbl + (size_t)i3 * D))[c];
        #pragma unroll
        for (int q = 0; q < 8; ++q)
            s[q] += (__half2float(r0.h[q]) + __half2float(r1.h[q]))
                  + (__half2float(r2.h[q]) + __half2float(r3.h[q]));
    }
    for (; k < e; ++k) {
        H8 r0;
        r0.u = ((const uint4*)(tbl + (size_t)cols[k] * D))[c];
        #pragma unroll
        for (int q = 0; q < 8; ++q) s[q] += __half2float(r0.h[q]);
    }
    float nsq = 0.f;
    #pragma unroll
    for (int q = 0; q < 8; ++q) nsq += s[q] * s[q];
    #pragma unroll
    for (int m = 1; m < 8; m <<= 1) nsq += __shfl_xor(nsq, m, 64);   // intra-group
    H8 o;
    #pragma unroll
    for (int q = 0; q < 8; ++q) o.h[q] = __float2half(s[q]);
    ((uint4*)(embH + (size_t)row * D))[c] = o.u;
    if (c == 0) invn[row] = 1.f / fmaxf(sqrtf(nsq), 1e-8f);
}

// ---------------- fused sims + prop-layer-1 USER side ----------------
// Group-per-user. Per edge: gather item row ONCE, dot -> sv, accumulate sv*row.
// Writes sims[k], diag[u], embB user rows.
__global__ void fsp1u_kernel(const __half* __restrict__ embA, const float* __restrict__ invn,
                             const int* __restrict__ i_idx, const int* __restrict__ pu,
                             float* __restrict__ sims, float* __restrict__ diag,
                             __half* __restrict__ embB) {
    int tid = blockIdx.x * blockDim.x + threadIdx.x;
    int wave = tid >> 6, lane = threadIdx.x & 63;
    int g = lane >> 3, c = lane & 7;
    int u = wave * 8 + g;
    if (u >= N_USERS) return;
    float invu = invn[u];
    H8 ur; ur.u = ((const uint4*)(embA + (size_t)u * D))[c];
    float un[8];
    #pragma unroll
    for (int q = 0; q < 8; ++q) un[q] = __half2float(ur.h[q]) * invu;
    float s[8];
    #pragma unroll
    for (int q = 0; q < 8; ++q) s[q] = 0.f;
    float dsum = 0.f;
    int b = pu[u], e = pu[u + 1];
    int k = b;
    for (; k + 3 < e; k += 4) {
        int i0 = i_idx[k], i1 = i_idx[k + 1], i2 = i_idx[k + 2], i3 = i_idx[k + 3];
        H8 r0, r1, r2, r3;
        r0.u = ((const uint4*)(embA + (size_t)(N_USERS + i0) * D))[c];
        r1.u = ((const uint4*)(embA + (size_t)(N_USERS + i1) * D))[c];
        r2.u = ((const uint4*)(embA + (size_t)(N_USERS + i2) * D))[c];
        r3.u = ((const uint4*)(embA + (size_t)(N_USERS + i3) * D))[c];
        float iv0 = invn[N_USERS + i0], iv1 = invn[N_USERS + i1];
        float iv2 = invn[N_USERS + i2], iv3 = invn[N_USERS + i3];
        float d0 = 0.f, d1 = 0.f, d2 = 0.f, d3 = 0.f;
        #pragma unroll
        for (int q = 0; q < 8; ++q) {
            d0 += un[q] * __half2float(r0.h[q]);
            d1 += un[q] * __half2float(r1.h[q]);
            d2 += un[q] * __half2float(r2.h[q]);
            d3 += un[q] * __half2float(r3.h[q]);
        }
        #pragma unroll
        for (int m = 1; m < 8; m <<= 1) {
            d0 += __shfl_xor(d0, m, 64); d1 += __shfl_xor(d1, m, 64);
            d2 += __shfl_xor(d2, m, 64); d3 += __shfl_xor(d3, m, 64);
        }
        float sv0 = (d0 * iv0 + 1.f) * 0.5f;
        float sv1 = (d1 * iv1 + 1.f) * 0.5f;
        float sv2 = (d2 * iv2 + 1.f) * 0.5f;
        float sv3 = (d3 * iv3 + 1.f) * 0.5f;
        if (c == 0) { sims[k] = sv0; sims[k + 1] = sv1; sims[k + 2] = sv2; sims[k + 3] = sv3; }
        dsum += (sv0 + sv1) + (sv2 + sv3);
        #pragma unroll
        for (int q = 0; q < 8; ++q)
            s[q] += (sv0 * __half2float(r0.h[q]) + sv1 * __half2float(r1.h[q]))
                  + (sv2 * __half2float(r2.h[q]) + sv3 * __half2float(r3.h[q]));
    }
    for (; k < e; ++k) {
        int i0 = i_idx[k];
        H8 r0;
        r0.u = ((const uint4*)(embA + (size_t)(N_USERS + i0) * D))[c];
        float iv0 = invn[N_USERS + i0];
        float d0 = 0.f;
        #pragma unroll
        for (int q = 0; q < 8; ++q) d0 += un[q] * __half2float(r0.h[q]);
        #pragma unroll
        for (int m = 1; m < 8; m <<= 1) d0 += __shfl_xor(d0, m, 64);
        float sv0 = (d0 * iv0 + 1.f) * 0.5f;
        if (c == 0) sims[k] = sv0;
        dsum += sv0;
        #pragma unroll
        for (int q = 0; q < 8; ++q) s[q] += sv0 * __half2float(r0.h[q]);
    }
    if (c == 0) diag[u] = dsum;
    float invd = 1.f / (dsum + 1e-7f);
    H8 o;
    #pragma unroll
    for (int q = 0; q < 8; ++q) o.h[q] = __float2half(s[q] * invd);
    ((uint4*)(embB + (size_t)u * D))[c] = o.u;
}

// ---------------- fused w2/diag + prop-layer-1 ITEM side ----------------
__global__ void p1i_kernel(const __half* __restrict__ embA, const float* __restrict__ sims,
                           const int* __restrict__ eids, const int* __restrict__ col2,
                           const int* __restrict__ pi, float* __restrict__ w2,
                           float* __restrict__ diag, __half* __restrict__ embB) {
    int tid = blockIdx.x * blockDim.x + threadIdx.x;
    int wave = tid >> 6, lane = threadIdx.x & 63;
    int g = lane >> 3, c = lane & 7;
    int i = wave * 8 + g;
    if (i >= N_ITEMS) return;
    float s[8];
    #pragma unroll
    for (int q = 0; q < 8; ++q) s[q] = 0.f;
    float dsum = 0.f;
    int b = pi[i], e = pi[i + 1];
    int k = b;
    for (; k + 3 < e; k += 4) {
        int e0 = eids[k], e1 = eids[k + 1], e2 = eids[k + 2], e3 = eids[k + 3];
        int u0 = col2[k], u1 = col2[k + 1], u2 = col2[k + 2], u3 = col2[k + 3];
        float w0 = sims[e0], w1 = sims[e1], w2v = sims[e2], w3v = sims[e3];
        H8 r0, r1, r2, r3;
        r0.u = ((const uint4*)(embA + (size_t)u0 * D))[c];
        r1.u = ((const uint4*)(embA + (size_t)u1 * D))[c];
        r2.u = ((const uint4*)(embA + (size_t)u2 * D))[c];
        r3.u = ((const uint4*)(embA + (size_t)u3 * D))[c];
        if (c == 0) { w2[k] = w0; w2[k + 1] = w1; w2[k + 2] = w2v; w2[k + 3] = w3v; }
        dsum += (w0 + w1) + (w2v + w3v);
        #pragma unroll
        for (int q = 0; q < 8; ++q)
            s[q] += (w0 * __half2float(r0.h[q]) + w1 * __half2float(r1.h[q]))
                  + (w2v * __half2float(r2.h[q]) + w3v * __half2float(r3.h[q]));
    }
    for (; k < e; ++k) {
        float w0 = sims[eids[k]];
        H8 r0;
        r0.u = ((const uint4*)(embA + (size_t)col2[k] * D))[c];
        if (c == 0) w2[k] = w0;
        dsum += w0;
        #pragma unroll
        for (int q = 0; q < 8; ++q) s[q] += w0 * __half2float(r0.h[q]);
    }
    if (c == 0) diag[N_USERS + i] = dsum;
    float invd = 1.f / (dsum + 1e-7f);
    H8 o;
    #pragma unroll
    for (int q = 0; q < 8; ++q) o.h[q] = __float2half(s[q] * invd);
    ((uint4*)(embB + (size_t)(N_USERS + i) * D))[c] = o.u;
}

// ---------------- propagation layers 2/3 (group-per-row; 4-way unrolled) ----------------
template <bool FINAL>
__global__ void prop_kernel(const __half* __restrict__ curH, __half* __restrict__ nextH,
                            const float* __restrict__ sims, const float* __restrict__ w2,
                            const float* __restrict__ diag,
                            const int* __restrict__ i_idx, const int* __restrict__ col2,
                            const int* __restrict__ pu, const int* __restrict__ pi,
                            const __half* __restrict__ e0, const __half* __restrict__ e1,
                            const __half* __restrict__ e2, float* __restrict__ out) {
    int tid = blockIdx.x * blockDim.x + threadIdx.x;
    int wave = tid >> 6, lane = threadIdx.x & 63;
    int g = lane >> 3, c = lane & 7;
    int row = wave * 8 + g;
    if (row >= N_TOTAL) return;
    float s[8];
    #pragma unroll
    for (int j = 0; j < 8; ++j) s[j] = 0.f;
    const int* cols; const float* ws; int b, e, colOff;
    if (row < N_USERS) { b = pu[row]; e = pu[row + 1]; cols = i_idx; ws = sims; colOff = N_USERS; }
    else { int i = row - N_USERS; b = pi[i]; e = pi[i + 1]; cols = col2; ws = w2; colOff = 0; }
    int k = b;
    for (; k + 3 < e; k += 4) {
        int i0 = cols[k] + colOff, i1 = cols[k + 1] + colOff,
            i2 = cols[k + 2] + colOff, i3 = cols[k + 3] + colOff;
        float w0 = ws[k], w1 = ws[k + 1], w2v = ws[k + 2], w3v = ws[k + 3];
        H8 r0, r1, r2, r3;
        r0.u = ((const uint4*)(curH + (size_t)i0 * D))[c];
        r1.u = ((const uint4*)(curH + (size_t)i1 * D))[c];
        r2.u = ((const uint4*)(curH + (size_t)i2 * D))[c];
        r3.u = ((const uint4*)(curH + (size_t)i3 * D))[c];
        #pragma unroll
        for (int q = 0; q < 8; ++q)
            s[q] += (w0 * __half2float(r0.h[q]) + w1 * __half2float(r1.h[q]))
                  + (w2v * __half2float(r2.h[q]) + w3v * __half2float(r3.h[q]));
    }
    for (; k < e; ++k) {
        float w0 = ws[k];
        H8 r0;
        r0.u = ((const uint4*)(curH + (size_t)(cols[k] + colOff) * D))[c];
        #pragma unroll
        for (int q = 0; q < 8; ++q) s[q] += w0 * __half2float(r0.h[q]);
    }
    float invd = 1.f / (diag[row] + 1e-7f);
    float v[8];
    #pragma unroll
    for (int q = 0; q < 8; ++q) v[q] = s[q] * invd;
    if (FINAL) {
        H8 r0, r1, r2;
        r0.u = ((const uint4*)(e0 + (size_t)row * D))[c];
        r1.u = ((const uint4*)(e1 + (size_t)row * D))[c];
        r2.u = ((const uint4*)(e2 + (size_t)row * D))[c];
        float o[8];
        #pragma unroll
        for (int q = 0; q < 8; ++q)
            o[q] = (v[q] + __half2float(r0.h[q]) + __half2float(r1.h[q]) + __half2float(r2.h[q])) * 0.25f;
        float4* op = (float4*)(out + (size_t)row * D);
        op[c * 2]     = make_float4(o[0], o[1], o[2], o[3]);
        op[c * 2 + 1] = make_float4(o[4], o[5], o[6], o[7]);
    } else {
        H8 o;
        #pragma unroll
        for (int q = 0; q < 8; ++q) o.h[q] = __float2half(v[q]);
        ((uint4*)(nextH + (size_t)row * D))[c] = o.u;
    }
}

// ---------------- launch ----------------

extern "C" void kernel_launch(void* const* d_in, const int* in_sizes, int n_in,
                              void* d_out, int out_size, void* d_ws, size_t ws_size,
                              hipStream_t stream) {
    const float* user_linear = (const float*)d_in[0];
    const float* item_linear = (const float*)d_in[1];
    const int* u_idx = (const int*)d_in[2];
    const int* i_idx = (const int*)d_in[3];
    const int nnz = in_sizes[2];

    // carve workspace (256B aligned)
    char* p = (char*)d_ws;
    auto carve = [&](size_t bytes) { void* r = (void*)p; p += (bytes + 255) & ~(size_t)255; return r; };
    __half* embA = (__half*)carve((size_t)N_TOTAL * D * 2);
    __half* embB = (__half*)carve((size_t)N_TOTAL * D * 2);
    __half* embC = (__half*)carve((size_t)N_TOTAL * D * 2);
    __half* ulH  = (__half*)carve((size_t)N_ITEMS * D * 2);
    __half* ilH  = (__half*)carve((size_t)N_USERS * D * 2);
    float* sims = (float*)carve((size_t)nnz * 4);
    float* w2   = (float*)carve((size_t)nnz * 4);
    float* diag = (float*)carve((size_t)N_TOTAL * 4);
    float* invn = (float*)carve((size_t)N_TOTAL * 4);
    int* pu   = (int*)carve((size_t)(N_USERS + 1) * 4);
    int* pi   = (int*)carve((size_t)(N_ITEMS + 1) * 4);
    int* eids = (int*)carve((size_t)nnz * 4);
    int* col2 = (int*)carve((size_t)nnz * 4);
    int* bcnt  = (int*)carve((size_t)(G_BKT + 1) * PAD * 4);
    int* bbase = (int*)carve((size_t)(G_BKT + 1) * PAD * 4);
    int* bcur  = (int*)carve((size_t)(G_BKT + 1) * PAD * 4);

    // staging aliases embA+embB (15.36MB >= 8MB); both dead until emb_kernel
    int2* tmp = (int2*)embA;

    float* out = (float*)d_out;  // [N_TOTAL, D]

    const int B = 256;

    // fused setup (tohalf x2, rowptr_u, bcnt zero) + CSR transpose
    setup_kernel<<<(ZTOT + B - 1) / B, B, 0, stream>>>(user_linear, item_linear, u_idx,
                                                       ulH, ilH, pu, bcnt, nnz);
    bcount_kernel<<<256, B, 0, stream>>>(i_idx, bcnt, nnz);
    bscan_kernel<<<1, 64, 0, stream>>>(bcnt, bbase, bcur, pi, nnz);
    p1_kernel<<<(nnz + B * 8 - 1) / (B * 8), B, 0, stream>>>(i_idx, u_idx, bcur, tmp, nnz);
    p2_kernel<<<G_BKT, B, 0, stream>>>(tmp, bbase, pi, eids, col2);

    // embeddings (+invnorm)  [overwrites tmp region — tmp dead now]
    int rowThreads = ((N_TOTAL + 7) / 8) * 64;            // 8 rows per wave
    emb_kernel<<<(rowThreads + B - 1) / B, B, 0, stream>>>(ulH, ilH, i_idx, col2,
                                                           pu, pi, embA, invn);

    // layer 1 fused: user side (sims+diag_u+prop) then item side (w2+diag_i+prop)
    int uThreads = ((N_USERS + 7) / 8) * 64;
    fsp1u_kernel<<<(uThreads + B - 1) / B, B, 0, stream>>>(embA, invn, i_idx, pu,
                                                           sims, diag, embB);
    int iThreads = ((N_ITEMS + 7) / 8) * 64;
    p1i_kernel<<<(iThreads + B - 1) / B, B, 0, stream>>>(embA, sims, eids, col2, pi,
                                                         w2, diag, embB);

    // layers 2 and 3; final fuses the 4-embedding mean into d_out
    prop_kernel<false><<<(rowThreads + B - 1) / B, B, 0, stream>>>(embB, embC, sims, w2, diag,
                                                                   i_idx, col2, pu, pi,
                                                                   nullptr, nullptr, nullptr, nullptr);
    prop_kernel<true><<<(rowThreads + B - 1) / B, B, 0, stream>>>(embC, nullptr, sims, w2, diag,
                                                                  i_idx, col2, pu, pi,
                                                                  embA, embB, embC, out);
}